// Round 16
// baseline (1973.127 us; speedup 1.0000x reference)
//
#include <hip/hip_runtime.h>
#include <math.h>

typedef unsigned short u16;
typedef float f32x4 __attribute__((ext_vector_type(4)));
typedef short bf16x8 __attribute__((ext_vector_type(8)));
typedef unsigned short us4 __attribute__((ext_vector_type(4)));

#define DEVI __device__ __forceinline__

DEVI float bf2f(u16 u) { return __uint_as_float(((unsigned int)u) << 16); }
DEVI u16 f2bf(float f) {
    unsigned int u = __float_as_uint(f);
    u += 0x7fffu + ((u >> 16) & 1u);
    return (u16)(u >> 16);
}

// ---------------------------------------------------------------- embedding
__global__ __launch_bounds__(256) void k_embed(const int* __restrict__ idx,
                                               const float* __restrict__ te,
                                               const float* __restrict__ pe,
                                               float* __restrict__ x) {
    int m = blockIdx.x;
    int t = m & 127;
    int tok = idx[m];
    const f32x4* a = (const f32x4*)(te + (long)tok * 1024);
    const f32x4* p = (const f32x4*)(pe + (long)t * 1024);
    f32x4* o = (f32x4*)(x + (long)m * 1024);
    o[threadIdx.x] = a[threadIdx.x] + p[threadIdx.x];
}

// ---------------------------------------------------------------- layernorm -> bf16 (shared body)
DEVI void ln_body(f32x4 v, const float* g, const float* b, float* red,
                  int tid, int lane, int wid, u16* outrow) {
    float s = v.x + v.y + v.z + v.w;
#pragma unroll
    for (int o2 = 32; o2; o2 >>= 1) s += __shfl_xor(s, o2);
    if (lane == 0) red[wid] = s;
    __syncthreads();
    float mean = (red[0] + red[1] + red[2] + red[3]) * (1.0f / 1024.0f);
    f32x4 d; d.x = v.x - mean; d.y = v.y - mean; d.z = v.z - mean; d.w = v.w - mean;
    float sq = d.x * d.x + d.y * d.y + d.z * d.z + d.w * d.w;
#pragma unroll
    for (int o2 = 32; o2; o2 >>= 1) sq += __shfl_xor(sq, o2);
    if (lane == 0) red[4 + wid] = sq;
    __syncthreads();
    float rstd = rsqrtf((red[4] + red[5] + red[6] + red[7]) * (1.0f / 1024.0f) + 1e-5f);
    f32x4 gg = ((const f32x4*)g)[tid];
    f32x4 bb = ((const f32x4*)b)[tid];
    us4 o4;
    o4.x = f2bf(d.x * rstd * gg.x + bb.x);
    o4.y = f2bf(d.y * rstd * gg.y + bb.y);
    o4.z = f2bf(d.z * rstd * gg.z + bb.z);
    o4.w = f2bf(d.w * rstd * gg.w + bb.w);
    ((us4*)outrow)[tid] = o4;
}

__global__ __launch_bounds__(256) void k_ln(const float* __restrict__ x,
                                            const float* __restrict__ g,
                                            const float* __restrict__ b,
                                            u16* __restrict__ out) {
    __shared__ float red[8];
    int tid = threadIdx.x, lane = tid & 63, wid = tid >> 6;
    int r = blockIdx.x;
    f32x4 v = ((const f32x4*)(x + (long)r * 1024))[tid];
    ln_body(v, g, b, red, tid, lane, wid, out + (long)r * 1024);
}

// combine split-K partials + residual + bias, update x, then LN -> bf16
__global__ __launch_bounds__(256) void k_comb_ln(float* __restrict__ x,
                                                 const float* __restrict__ p01,
                                                 const float* __restrict__ bias,
                                                 const float* __restrict__ g,
                                                 const float* __restrict__ b,
                                                 u16* __restrict__ out) {
    __shared__ float red[8];
    int tid = threadIdx.x, lane = tid & 63, wid = tid >> 6;
    int r = blockIdx.x;
    f32x4 v = ((const f32x4*)(x + (long)r * 1024))[tid];
    f32x4 p0 = ((const f32x4*)(p01 + (long)r * 1024))[tid];
    f32x4 p1 = ((const f32x4*)(p01 + 2048L * 1024 + (long)r * 1024))[tid];
    f32x4 bv = ((const f32x4*)bias)[tid];
    v.x += p0.x + p1.x + bv.x; v.y += p0.y + p1.y + bv.y;
    v.z += p0.z + p1.z + bv.z; v.w += p0.w + p1.w + bv.w;
    ((f32x4*)(x + (long)r * 1024))[tid] = v;
    ln_body(v, g, b, red, tid, lane, wid, out + (long)r * 1024);
}

// ---------------------------------------------------------------- transpose + cvt f32[K][N] -> bf16[N][K]
DEVI void tr_tile(const float* __restrict__ in, u16* __restrict__ out,
                  int K, int N, int k0, int n0, int tid, float (*tile)[65]) {
    int trow = tid >> 4;
    int tcol = (tid & 15) * 4;
#pragma unroll
    for (int p = 0; p < 4; ++p) {
        int k = k0 + trow + p * 16;
        const float* src = in + (long)k * N + n0 + tcol;
#pragma unroll
        for (int j = 0; j < 4; ++j) {
            int n = n0 + tcol + j;
            tile[trow + p * 16][tcol + j] = (n < N) ? src[j] : 0.0f;
        }
    }
    __syncthreads();
#pragma unroll
    for (int p = 0; p < 4; ++p) {
        int n = n0 + trow + p * 16;
        if (n < N) {
            us4 o4;
#pragma unroll
            for (int j = 0; j < 4; ++j) o4[j] = f2bf(tile[tcol + j][trow + p * 16]);
            *(us4*)(out + (long)n * K + k0 + tcol) = o4;
        }
    }
}

__global__ __launch_bounds__(256) void k_tr_one(const float* __restrict__ in,
                                                u16* __restrict__ out, int K, int N) {
    __shared__ float tile[64][65];
    tr_tile(in, out, K, N, blockIdx.y * 64, blockIdx.x * 64, threadIdx.x, tile);
}

__global__ __launch_bounds__(256) void k_tr_layer(
    const float* __restrict__ wq, const float* __restrict__ wk,
    const float* __restrict__ wv, const float* __restrict__ wp,
    const float* __restrict__ f1, const float* __restrict__ f2,
    u16* __restrict__ oqkv, u16* __restrict__ oproj,
    u16* __restrict__ of1, u16* __restrict__ of2) {
    __shared__ float tile[64][65];
    int id = blockIdx.x;
    const float* in; u16* out; int K, N, txx, tyy;
    if (id < 1024) {
        int t = id >> 8, s2 = id & 255;
        txx = s2 & 15; tyy = s2 >> 4; K = 1024; N = 1024;
        in = (t == 0) ? wq : (t == 1) ? wk : (t == 2) ? wv : wp;
        out = (t == 3) ? oproj : oqkv + (long)t * 1024 * 1024;
    } else if (id < 2048) {
        int s2 = id - 1024;
        txx = s2 & 63; tyy = s2 >> 6; K = 1024; N = 4096; in = f1; out = of1;
    } else {
        int s2 = id - 2048;
        txx = s2 & 15; tyy = s2 >> 4; K = 4096; N = 1024; in = f2; out = of2;
    }
    tr_tile(in, out, K, N, tyy * 64, txx * 64, threadIdx.x, tile);
}

// ---------------------------------------------------------------- staging (XOR-swizzled, global_load_lds 16B)
// 64-col tiles, 256 threads (8 chunks/row, slot ^= row&7) — measured 0-conflict frag pattern
template <int ROWS>
DEVI void stage_tile(const u16* __restrict__ g, long row0, long rowmax, int ld,
                     int col0, char* lds, int tid) {
    constexpr int NCH = ROWS * 8;
#pragma unroll
    for (int p = 0; p < NCH / 256; ++p) {
        int c = tid + p * 256;
        int row = c >> 3;
        int gslot = c & 7;
        int gdata = gslot ^ (row & 7);
        long gr = row0 + row;
        if (gr > rowmax) gr = rowmax;
        const u16* src = g + gr * (long)ld + col0 + gdata * 8;
        char* dst = lds + ((long)((tid & 192) + p * 256)) * 16;
        __builtin_amdgcn_global_load_lds(
            (const __attribute__((address_space(1))) void*)src,
            (__attribute__((address_space(3))) void*)dst, 16, 0, 0);
    }
}

// 32-col tiles, 512 threads (4 chunks/row). Data chunk d stored at slot s=(d+(row>>1))&3;
// frag read slot=(l4+(row>>1))&3: per 16-lane group rows 0-7 cover all 32 banks once,
// rows 8-15 repeat -> exactly 2-way aliasing = free (m136, verified r13/r14).
template <int ROWS>
DEVI void stage32b512(const u16* __restrict__ g, long row0, long rowmax, int ld,
                      int col0, char* lds, int tid) {
    constexpr int NP = ROWS * 4 / 512;
#pragma unroll
    for (int p = 0; p < NP; ++p) {
        int c = tid + p * 512;
        int row = c >> 2;
        int gslot = c & 3;
        int gdata = (gslot - (row >> 1)) & 3;
        long gr = row0 + row;
        if (gr > rowmax) gr = rowmax;
        const u16* src = g + gr * (long)ld + col0 + gdata * 8;
        char* dst = lds + ((long)((tid & 448) + p * 512)) * 16;
        __builtin_amdgcn_global_load_lds(
            (const __attribute__((address_space(1))) void*)src,
            (__attribute__((address_space(3))) void*)dst, 16, 0, 0);
    }
}

// ---------------------------------------------------------------- per-layer GEMM (128 x BN, m97 structure)
template <int BN, int OCC, bool OUT_BF16, bool RELU, bool HAS_BIAS, bool HAS_RES, bool SPLITK>
__global__ __launch_bounds__(256, OCC) void k_gemm(
    const u16* __restrict__ A, const u16* __restrict__ Bt,
    const float* __restrict__ bias, const float* __restrict__ res,
    float* __restrict__ Cf, u16* __restrict__ Cb,
    int M, int N, int K, int ldk, int ldc) {
    constexpr int NR = BN / 32;
    constexpr int ASZ = 128 * 64 * 2;
    constexpr int BSZ = BN * 64 * 2;
    __shared__ __align__(16) char lds[2 * (ASZ + BSZ)];
    int tid = threadIdx.x, lane = tid & 63, wid = tid >> 6;
    int l15 = lane & 15, l4 = lane >> 4;
    int wr = wid >> 1, wc = wid & 1;
    if constexpr (SPLITK) {
        int h = blockIdx.z;
        A += (long)h * K;
        Bt += (long)h * K;
        Cf += (long)h * M * (long)ldc;
    }
    long m0 = (long)blockIdx.y * 128;
    long n0 = (long)blockIdx.x * BN;
    f32x4 acc[4][NR] = {};
    const int nk = K >> 6;

    stage_tile<128>(A, m0, (long)M - 1, ldk, 0, lds, tid);
    stage_tile<BN>(Bt, n0, (long)N - 1, ldk, 0, lds + ASZ, tid);
    int cur = 0;
    for (int kt = 0; kt < nk; ++kt) {
        __syncthreads();
        if (kt + 1 < nk) {
            char* nb = lds + (cur ^ 1) * (ASZ + BSZ);
            stage_tile<128>(A, m0, (long)M - 1, ldk, (kt + 1) << 6, nb, tid);
            stage_tile<BN>(Bt, n0, (long)N - 1, ldk, (kt + 1) << 6, nb + ASZ, tid);
        }
        const char* ab = lds + cur * (ASZ + BSZ);
        const char* bb = ab + ASZ;
#pragma unroll
        for (int kh = 0; kh < 2; ++kh) {
            bf16x8 af[4], bfv[NR];
#pragma unroll
            for (int mi = 0; mi < 4; ++mi) {
                int row = wr * 64 + mi * 16 + l15;
                int slot = (kh * 4 + l4) ^ (row & 7);
                af[mi] = *(const bf16x8*)(ab + (row * 8 + slot) * 16);
            }
#pragma unroll
            for (int ni = 0; ni < NR; ++ni) {
                int row = wc * (BN / 2) + ni * 16 + l15;
                int slot = (kh * 4 + l4) ^ (row & 7);
                bfv[ni] = *(const bf16x8*)(bb + (row * 8 + slot) * 16);
            }
#pragma unroll
            for (int mi = 0; mi < 4; ++mi)
#pragma unroll
                for (int ni = 0; ni < NR; ++ni)
                    acc[mi][ni] = __builtin_amdgcn_mfma_f32_16x16x32_bf16(
                        af[mi], bfv[ni], acc[mi][ni], 0, 0, 0);
        }
        cur ^= 1;
    }
#pragma unroll
    for (int ni = 0; ni < NR; ++ni) {
        long n = n0 + wc * (BN / 2) + ni * 16 + l15;
        if (n < N) {
            float bv = HAS_BIAS ? bias[n] : 0.0f;
#pragma unroll
            for (int mi = 0; mi < 4; ++mi) {
#pragma unroll
                for (int j = 0; j < 4; ++j) {
                    long m = m0 + wr * 64 + mi * 16 + l4 * 4 + j;
                    float v = acc[mi][ni][j] + bv;
                    if (HAS_RES) v += res[m * (long)ldc + n];
                    if (RELU) v = fmaxf(v, 0.0f);
                    if (OUT_BF16) Cb[m * (long)ldc + n] = f2bf(v);
                    else Cf[m * (long)ldc + n] = v;
                }
            }
        }
    }
}

// ---------------------------------------------------------------- 256x128 layer GEMM (head's verified main loop,
// BK=32, 512 threads, 48 KB LDS -> up to 3 blocks/CU, conflict-free swizzle) with a plain
// bias/ReLU/bf16 epilogue. For qkv (N=3072) and fc1 (N=4096); M=2048, N multiples of 128/256
// so no bounds paths.
template <bool RELU, bool HAS_BIAS>
__global__ __launch_bounds__(512, 2) void k_gemm256(
    const u16* __restrict__ A, const u16* __restrict__ Bt,
    const float* __restrict__ bias, u16* __restrict__ Cb,
    int M, int N, int K, int ldc) {
    constexpr int ASZ = 256 * 32 * 2;      // 16 KB
    constexpr int BSZ = 128 * 32 * 2;      // 8 KB
    constexpr int TSZ = ASZ + BSZ;         // 24 KB
    __shared__ __align__(16) char lds[2 * TSZ];   // 48 KB
    int tid = threadIdx.x, lane = tid & 63, wid = tid >> 6;
    int l15 = lane & 15, l4 = lane >> 4;
    int wr = wid >> 1, wc = wid & 1;       // 4 x 2 waves; wave owns 64 x 64
    long m0 = (long)blockIdx.y * 256, n0 = (long)blockIdx.x * 128;
    f32x4 acc[4][4] = {};
    const int nk = K >> 5;                 // 32 for K=1024

    stage32b512<256>(A, m0, (long)M - 1, K, 0, lds, tid);
    stage32b512<128>(Bt, n0, (long)N - 1, K, 0, lds + ASZ, tid);
    int cur = 0;
    for (int kt = 0; kt < nk; ++kt) {
        __syncthreads();
        if (kt + 1 < nk) {
            char* nb = lds + (cur ^ 1) * TSZ;
            stage32b512<256>(A, m0, (long)M - 1, K, (kt + 1) << 5, nb, tid);
            stage32b512<128>(Bt, n0, (long)N - 1, K, (kt + 1) << 5, nb + ASZ, tid);
        }
        const char* ab = lds + cur * TSZ;
        const char* bb = ab + ASZ;
        bf16x8 af[4], bfv[4];
#pragma unroll
        for (int mi = 0; mi < 4; ++mi) {
            int row = wr * 64 + mi * 16 + l15;             // 0..255
            int slot = (l4 + (row >> 1)) & 3;
            af[mi] = *(const bf16x8*)(ab + (row * 4 + slot) * 16);
        }
#pragma unroll
        for (int ni = 0; ni < 4; ++ni) {
            int row = wc * 64 + ni * 16 + l15;             // 0..127
            int slot = (l4 + (row >> 1)) & 3;
            bfv[ni] = *(const bf16x8*)(bb + (row * 4 + slot) * 16);
        }
#pragma unroll
        for (int mi = 0; mi < 4; ++mi)
#pragma unroll
            for (int ni = 0; ni < 4; ++ni)
                acc[mi][ni] = __builtin_amdgcn_mfma_f32_16x16x32_bf16(
                    af[mi], bfv[ni], acc[mi][ni], 0, 0, 0);
        cur ^= 1;
    }
    // epilogue: bias + optional ReLU, bf16 out
#pragma unroll
    for (int ni = 0; ni < 4; ++ni) {
        long n = n0 + wc * 64 + ni * 16 + l15;
        float bv = HAS_BIAS ? bias[n] : 0.0f;
#pragma unroll
        for (int mi = 0; mi < 4; ++mi) {
#pragma unroll
            for (int j = 0; j < 4; ++j) {
                long m = m0 + wr * 64 + mi * 16 + l4 * 4 + j;
                float v = acc[mi][ni][j] + bv;
                if (RELU) v = fmaxf(v, 0.0f);
                Cb[m * (long)ldc + n] = f2bf(v);
            }
        }
    }
}

// ---------------------------------------------------------------- head GEMM (r14 best: 256x128, BK=32, 512 thr,
// 66 KB -> 2 blocks/CU, conflict-free swizzle, spread grid, two-pass bounce epilogue + NT stores + LSE)
__global__ __launch_bounds__(512, 2) void k_head(
    const u16* __restrict__ A, const u16* __restrict__ Bt,
    const float* __restrict__ bias, float* __restrict__ Cf,
    float2* __restrict__ part, int M, int N, int K, int ldc) {
    constexpr int ASZ = 256 * 32 * 2;      // 16 KB
    constexpr int BSZ = 128 * 32 * 2;      // 8 KB
    constexpr int TSZ = ASZ + BSZ;         // 24 KB
    __shared__ __align__(16) char lds[128 * 129 * 4];
    int tid = threadIdx.x, lane = tid & 63, wid = tid >> 6;
    int l15 = lane & 15, l4 = lane >> 4;
    int wr = wid >> 1, wc = wid & 1;       // 4 x 2 waves; wave owns 64 x 64
    int bn = blockIdx.x, bm = blockIdx.y;
    long m0 = (long)bm * 256, n0 = (long)bn * 128;
    f32x4 acc[4][4] = {};
    const int nk = K >> 5;                 // 32

    stage32b512<256>(A, m0, (long)M - 1, K, 0, lds, tid);
    stage32b512<128>(Bt, n0, (long)N - 1, K, 0, lds + ASZ, tid);
    int cur = 0;
    for (int kt = 0; kt < nk; ++kt) {
        __syncthreads();
        if (kt + 1 < nk) {
            char* nb = lds + (cur ^ 1) * TSZ;
            stage32b512<256>(A, m0, (long)M - 1, K, (kt + 1) << 5, nb, tid);
            stage32b512<128>(Bt, n0, (long)N - 1, K, (kt + 1) << 5, nb + ASZ, tid);
        }
        const char* ab = lds + cur * TSZ;
        const char* bb = ab + ASZ;
        bf16x8 af[4], bfv[4];
#pragma unroll
        for (int mi = 0; mi < 4; ++mi) {
            int row = wr * 64 + mi * 16 + l15;
            int slot = (l4 + (row >> 1)) & 3;
            af[mi] = *(const bf16x8*)(ab + (row * 4 + slot) * 16);
        }
#pragma unroll
        for (int ni = 0; ni < 4; ++ni) {
            int row = wc * 64 + ni * 16 + l15;
            int slot = (l4 + (row >> 1)) & 3;
            bfv[ni] = *(const bf16x8*)(bb + (row * 4 + slot) * 16);
        }
#pragma unroll
        for (int mi = 0; mi < 4; ++mi)
#pragma unroll
            for (int ni = 0; ni < 4; ++ni)
                acc[mi][ni] = __builtin_amdgcn_mfma_f32_16x16x32_bf16(
                    af[mi], bfv[ni], acc[mi][ni], 0, 0, 0);
        cur ^= 1;
    }
    const float BIG_NEG = -1e30f;
    float bvv[4];
#pragma unroll
    for (int ni = 0; ni < 4; ++ni) {
        long n = n0 + wc * 64 + ni * 16 + l15;
        bvv[ni] = (n < N) ? bias[n] : 0.0f;
    }
    float* ldsF = (float*)lds;             // [128][129]
#pragma unroll
    for (int pass = 0; pass < 2; ++pass) {
        int rbase = pass * 128;
        __syncthreads();
        if ((wr >> 1) == pass) {
#pragma unroll
            for (int mi = 0; mi < 4; ++mi)
#pragma unroll
                for (int ni = 0; ni < 4; ++ni)
#pragma unroll
                    for (int j = 0; j < 4; ++j) {
                        int row = wr * 64 + mi * 16 + l4 * 4 + j - rbase;
                        int col = wc * 64 + ni * 16 + l15;
                        long n = n0 + col;
                        float v = acc[mi][ni][j] + bvv[ni];
                        if (n >= N) v = BIG_NEG;
                        ldsF[row * 129 + col] = v;
                    }
        }
        __syncthreads();
#pragma unroll 4
        for (int i = 0; i < 32; ++i) {
            int flat = tid + (i << 9);
            int row = flat >> 7, col = flat & 127;
            long n = n0 + col;
            if (n < N)
                __builtin_nontemporal_store(ldsF[row * 129 + col],
                                            &Cf[(m0 + rbase + row) * (long)ldc + n]);
        }
        if (tid < 256) {
            int r = tid >> 1, half = tid & 1;
            const float* rp = ldsF + r * 129 + half * 64;
            float mx = BIG_NEG;
#pragma unroll 8
            for (int c = 0; c < 64; ++c) mx = fmaxf(mx, rp[c]);
            float sm = 0.f;
#pragma unroll 8
            for (int c = 0; c < 64; ++c) sm += __expf(rp[c] - mx);
            float mo = __shfl_xor(mx, 1), so = __shfl_xor(sm, 1);
            float nm = fmaxf(mx, mo);
            float S = sm * __expf(mx - nm) + so * __expf(mo - nm);
            if (half == 0)
                part[(long)bn * M + m0 + rbase + r] = make_float2(nm, S);
        }
    }
}

// ---------------------------------------------------------------- MFMA attention
__global__ __launch_bounds__(256) void k_attn_mfma(const u16* __restrict__ qkv,
                                                   u16* __restrict__ o) {
    __shared__ __align__(16) u16 Ks[128 * 64];
    __shared__ __align__(16) u16 Vt[64 * 128];
    __shared__ __align__(16) u16 Ps[4][32 * 128];
    int tid = threadIdx.x, lane = tid & 63, w = tid >> 6;
    int l15 = lane & 15, l4 = lane >> 4;
    int b = blockIdx.x >> 4, h = blockIdx.x & 15;
    const u16* base = qkv + (long)b * 128 * 3072 + h * 64;

    stage_tile<128>(base + 1024, 0, 127, 3072, 0, (char*)Ks, tid);
    {
        const u16* vg = base + 2048;
#pragma unroll
        for (int p = 0; p < 4; ++p) {
            int s0 = (w * 4 + p) * 8;
            u16 tmp[8];
#pragma unroll
            for (int j = 0; j < 8; ++j) tmp[j] = vg[(long)(s0 + j) * 3072 + lane];
            int slot = (s0 >> 3) ^ (lane & 7);
            *(bf16x8*)((char*)Vt + lane * 256 + slot * 16) = *(bf16x8*)tmp;
        }
    }
    bf16x8 aq[2][2];
#pragma unroll
    for (int mj = 0; mj < 2; ++mj)
#pragma unroll
        for (int kk = 0; kk < 2; ++kk)
            aq[mj][kk] = *(const bf16x8*)(base + (long)(w * 32 + mj * 16 + l15) * 3072 + kk * 32 + l4 * 8);
    __syncthreads();

    f32x4 sacc[2][8] = {};
#pragma unroll
    for (int sj = 0; sj < 8; ++sj) {
        bf16x8 bk[2];
#pragma unroll
        for (int kk = 0; kk < 2; ++kk) {
            int row = sj * 16 + l15;
            int slot = (kk * 4 + l4) ^ (row & 7);
            bk[kk] = *(const bf16x8*)((char*)Ks + (row * 8 + slot) * 16);
        }
#pragma unroll
        for (int mj = 0; mj < 2; ++mj) {
            sacc[mj][sj] = __builtin_amdgcn_mfma_f32_16x16x32_bf16(aq[mj][0], bk[0], sacc[mj][sj], 0, 0, 0);
            sacc[mj][sj] = __builtin_amdgcn_mfma_f32_16x16x32_bf16(aq[mj][1], bk[1], sacc[mj][sj], 0, 0, 0);
        }
    }
    const float scale = 0.03125f;
#pragma unroll
    for (int mj = 0; mj < 2; ++mj) {
#pragma unroll
        for (int j = 0; j < 4; ++j) {
            int tq = w * 32 + mj * 16 + l4 * 4 + j;
            float mx = -INFINITY;
#pragma unroll
            for (int sj = 0; sj < 8; ++sj) {
                int s = sj * 16 + l15;
                float v = (s <= tq) ? sacc[mj][sj][j] * scale : -INFINITY;
                sacc[mj][sj][j] = v;
                mx = fmaxf(mx, v);
            }
#pragma unroll
            for (int ofs = 1; ofs < 16; ofs <<= 1) mx = fmaxf(mx, __shfl_xor(mx, ofs));
            float sm = 0.f;
#pragma unroll
            for (int sj = 0; sj < 8; ++sj) {
                float e = __expf(sacc[mj][sj][j] - mx);
                sacc[mj][sj][j] = e;
                sm += e;
            }
#pragma unroll
            for (int ofs = 1; ofs < 16; ofs <<= 1) sm += __shfl_xor(sm, ofs);
            float inv = 1.0f / sm;
            int m2 = mj * 16 + l4 * 4 + j;
            u16* prow = Ps[w] + m2 * 128;
#pragma unroll
            for (int sj = 0; sj < 8; ++sj) {
                int s = sj * 16 + l15;
                int slot = (s >> 3) ^ (m2 & 7);
                prow[slot * 8 + (s & 7)] = f2bf(sacc[mj][sj][j] * inv);
            }
        }
    }
    f32x4 oacc[2][4] = {};
#pragma unroll
    for (int kk = 0; kk < 4; ++kk) {
        bf16x8 pa[2], bv[4];
#pragma unroll
        for (int mj = 0; mj < 2; ++mj) {
            int m2 = mj * 16 + l15;
            int slot = (kk * 4 + l4) ^ (m2 & 7);
            pa[mj] = *(const bf16x8*)((char*)(Ps[w]) + m2 * 256 + slot * 16);
        }
#pragma unroll
        for (int nb = 0; nb < 4; ++nb) {
            int d = nb * 16 + l15;
            int slot = (kk * 4 + l4) ^ (d & 7);
            bv[nb] = *(const bf16x8*)((char*)Vt + d * 256 + slot * 16);
        }
#pragma unroll
        for (int mj = 0; mj < 2; ++mj)
#pragma unroll
            for (int nb = 0; nb < 4; ++nb)
                oacc[mj][nb] = __builtin_amdgcn_mfma_f32_16x16x32_bf16(pa[mj], bv[nb], oacc[mj][nb], 0, 0, 0);
    }
#pragma unroll
    for (int mj = 0; mj < 2; ++mj)
#pragma unroll
        for (int nb = 0; nb < 4; ++nb) {
            int d = nb * 16 + l15;
#pragma unroll
            for (int j = 0; j < 4; ++j) {
                int tq = w * 32 + mj * 16 + l4 * 4 + j;
                o[((long)b * 128 + tq) * 1024 + h * 64 + d] = f2bf(oacc[mj][nb][j]);
            }
        }
}

// ---------------------------------------------------------------- loss from partials (part layout: [bn][2048])
__global__ __launch_bounds__(64) void k_loss_rows2(const float2* __restrict__ part,
                                                   const float* __restrict__ logits,
                                                   const int* __restrict__ tgt,
                                                   float* __restrict__ rowloss, int ncb) {
    int r = blockIdx.x, lane = threadIdx.x;
    float M = -1e30f, S = 0.f;
    for (int cb = lane; cb < ncb; cb += 64) {
        float2 p = part[(long)cb * 2048 + r];
        float nm = fmaxf(M, p.x);
        S = S * __expf(M - nm) + p.y * __expf(p.x - nm);
        M = nm;
    }
#pragma unroll
    for (int ofs = 32; ofs; ofs >>= 1) {
        float M2 = __shfl_xor(M, ofs), S2 = __shfl_xor(S, ofs);
        float nm = fmaxf(M, M2);
        S = S * __expf(M - nm) + S2 * __expf(M2 - nm);
        M = nm;
    }
    if (lane == 0)
        rowloss[r] = (M + logf(S)) - logits[(long)r * 50257 + tgt[r]];
}

__global__ __launch_bounds__(256) void k_loss_reduce(const float* __restrict__ rowloss,
                                                     float* __restrict__ out) {
    __shared__ float red[4];
    int tid = threadIdx.x, lane = tid & 63, wid = tid >> 6;
    float s = 0.f;
    for (int i = tid; i < 2048; i += 256) s += rowloss[i];
#pragma unroll
    for (int ofs = 32; ofs; ofs >>= 1) s += __shfl_xor(s, ofs);
    if (lane == 0) red[wid] = s;
    __syncthreads();
    if (tid == 0) out[0] = (red[0] + red[1] + red[2] + red[3]) * (1.0f / 2048.0f);
}

// ---------------------------------------------------------------- host
extern "C" void kernel_launch(void* const* d_in, const int* in_sizes, int n_in,
                              void* d_out, int out_size, void* d_ws, size_t ws_size,
                              hipStream_t stream) {
    (void)in_sizes; (void)n_in; (void)out_size; (void)ws_size;
    const int*   idx     = (const int*)d_in[0];
    const int*   targets = (const int*)d_in[1];
    const float* tok_emb = (const float*)d_in[2];
    const float* pos_emb = (const float*)d_in[3];
    const float* wq      = (const float*)d_in[4];
    const float* wk      = (const float*)d_in[5];
    const float* wv      = (const float*)d_in[6];
    const float* w_proj  = (const float*)d_in[7];
    const float* b_proj  = (const float*)d_in[8];
    const float* ln1_g   = (const float*)d_in[9];
    const float* ln1_b   = (const float*)d_in[10];
    const float* ln2_g   = (const float*)d_in[11];
    const float* ln2_b   = (const float*)d_in[12];
    const float* w_fc1   = (const float*)d_in[13];
    const float* b_fc1   = (const float*)d_in[14];
    const float* w_fc2   = (const float*)d_in[15];
    const float* b_fc2   = (const float*)d_in[16];
    const float* lnf_g   = (const float*)d_in[17];
    const float* lnf_b   = (const float*)d_in[18];
    const float* w_head  = (const float*)d_in[19];
    const float* b_head  = (const float*)d_in[20];
    float* out = (float*)d_out;

    char* w = (char*)d_ws;
    auto alloc = [&](size_t bytes) {
        char* p = w;
        w += (bytes + 255) & ~(size_t)255;
        return p;
    };
    u16*    wT_qkv  = (u16*)alloc(3072L * 1024 * 2);
    u16*    wT_proj = (u16*)alloc(1024L * 1024 * 2);
    u16*    wT_f1   = (u16*)alloc(4096L * 1024 * 2);
    u16*    wT_f2   = (u16*)alloc(1024L * 4096 * 2);
    u16*    wT_head = (u16*)alloc(50257L * 1024 * 2);
    float*  x       = (float*)alloc(2048L * 1024 * 4);
    u16*    h_bf    = (u16*)alloc(2048L * 1024 * 2);
    u16*    qkvb    = (u16*)alloc(2048L * 3072 * 2);
    u16*    o_bf    = (u16*)alloc(2048L * 1024 * 2);
    u16*    ff_bf   = (u16*)alloc(2048L * 4096 * 2);
    float*  p01     = (float*)alloc(2L * 2048 * 1024 * 4);   // split-K partials
    float2* part    = (float2*)alloc(393L * 2048 * 8);
    float*  rowloss = (float*)alloc(2048L * 4);

    k_embed<<<2048, 256, 0, stream>>>(idx, tok_emb, pos_emb, x);
    k_tr_one<<<dim3(786, 16), 256, 0, stream>>>(w_head, wT_head, 1024, 50257);

    for (int l = 0; l < 12; ++l) {
        k_tr_layer<<<3072, 256, 0, stream>>>(
            wq + (long)l * 1048576, wk + (long)l * 1048576,
            wv + (long)l * 1048576, w_proj + (long)l * 1048576,
            w_fc1 + (long)l * 4194304, w_fc2 + (long)l * 4194304,
            wT_qkv, wT_proj, wT_f1, wT_f2);
        if (l == 0)
            k_ln<<<2048, 256, 0, stream>>>(x, ln1_g, ln1_b, h_bf);
        else
            k_comb_ln<<<2048, 256, 0, stream>>>(x, p01, b_fc2 + (l - 1) * 1024,
                                                ln1_g + l * 1024, ln1_b + l * 1024, h_bf);
        k_gemm256<false, false><<<dim3(24, 8), 512, 0, stream>>>(
            h_bf, wT_qkv, nullptr, qkvb, 2048, 3072, 1024, 3072);
        k_attn_mfma<<<256, 256, 0, stream>>>(qkvb, o_bf);
        // proj split-K x2 at 3 blocks/CU; combine + b_proj fused into ln2 comb
        k_gemm<64, 3, false, false, false, false, true><<<dim3(16, 16, 2), 256, 0, stream>>>(
            o_bf, wT_proj, nullptr, nullptr, p01, nullptr, 2048, 1024, 512, 1024, 1024);
        k_comb_ln<<<2048, 256, 0, stream>>>(x, p01, b_proj + l * 1024,
                                            ln2_g + l * 1024, ln2_b + l * 1024, h_bf);
        k_gemm256<true, true><<<dim3(32, 8), 512, 0, stream>>>(
            h_bf, wT_f1, b_fc1 + l * 4096, ff_bf, 2048, 4096, 1024, 4096);
        // fc2 split-K x2 at 3 blocks/CU; combine fused into next layer's ln1 comb (or final lnf)
        k_gemm<64, 3, false, false, false, false, true><<<dim3(16, 16, 2), 256, 0, stream>>>(
            ff_bf, wT_f2, nullptr, nullptr, p01, nullptr, 2048, 1024, 2048, 4096, 1024);
    }
    k_comb_ln<<<2048, 256, 0, stream>>>(x, p01, b_fc2 + 11 * 1024, lnf_g, lnf_b, h_bf);
    k_head<<<dim3(393, 8), 512, 0, stream>>>(h_bf, wT_head, b_head, out, part,
                                             2048, 50257, 1024, 50257);
    k_loss_rows2<<<2048, 64, 0, stream>>>(part, out, targets, rowloss, 393);
    k_loss_reduce<<<1, 256, 0, stream>>>(rowloss, out + 102926336L);
}

// Round 17
// 1831.337 us; speedup vs baseline: 1.0774x; 1.0774x over previous
//
#include <hip/hip_runtime.h>
#include <math.h>

typedef unsigned short u16;
typedef float f32x4 __attribute__((ext_vector_type(4)));
typedef short bf16x8 __attribute__((ext_vector_type(8)));
typedef unsigned short us4 __attribute__((ext_vector_type(4)));

#define DEVI __device__ __forceinline__

DEVI float bf2f(u16 u) { return __uint_as_float(((unsigned int)u) << 16); }
DEVI u16 f2bf(float f) {
    unsigned int u = __float_as_uint(f);
    u += 0x7fffu + ((u >> 16) & 1u);
    return (u16)(u >> 16);
}

// ---------------------------------------------------------------- embedding
__global__ __launch_bounds__(256) void k_embed(const int* __restrict__ idx,
                                               const float* __restrict__ te,
                                               const float* __restrict__ pe,
                                               float* __restrict__ x) {
    int m = blockIdx.x;
    int t = m & 127;
    int tok = idx[m];
    const f32x4* a = (const f32x4*)(te + (long)tok * 1024);
    const f32x4* p = (const f32x4*)(pe + (long)t * 1024);
    f32x4* o = (f32x4*)(x + (long)m * 1024);
    o[threadIdx.x] = a[threadIdx.x] + p[threadIdx.x];
}

// ---------------------------------------------------------------- layernorm -> bf16 (shared body)
DEVI void ln_body(f32x4 v, const float* g, const float* b, float* red,
                  int tid, int lane, int wid, u16* outrow) {
    float s = v.x + v.y + v.z + v.w;
#pragma unroll
    for (int o2 = 32; o2; o2 >>= 1) s += __shfl_xor(s, o2);
    if (lane == 0) red[wid] = s;
    __syncthreads();
    float mean = (red[0] + red[1] + red[2] + red[3]) * (1.0f / 1024.0f);
    f32x4 d; d.x = v.x - mean; d.y = v.y - mean; d.z = v.z - mean; d.w = v.w - mean;
    float sq = d.x * d.x + d.y * d.y + d.z * d.z + d.w * d.w;
#pragma unroll
    for (int o2 = 32; o2; o2 >>= 1) sq += __shfl_xor(sq, o2);
    if (lane == 0) red[4 + wid] = sq;
    __syncthreads();
    float rstd = rsqrtf((red[4] + red[5] + red[6] + red[7]) * (1.0f / 1024.0f) + 1e-5f);
    f32x4 gg = ((const f32x4*)g)[tid];
    f32x4 bb = ((const f32x4*)b)[tid];
    us4 o4;
    o4.x = f2bf(d.x * rstd * gg.x + bb.x);
    o4.y = f2bf(d.y * rstd * gg.y + bb.y);
    o4.z = f2bf(d.z * rstd * gg.z + bb.z);
    o4.w = f2bf(d.w * rstd * gg.w + bb.w);
    ((us4*)outrow)[tid] = o4;
}

__global__ __launch_bounds__(256) void k_ln(const float* __restrict__ x,
                                            const float* __restrict__ g,
                                            const float* __restrict__ b,
                                            u16* __restrict__ out) {
    __shared__ float red[8];
    int tid = threadIdx.x, lane = tid & 63, wid = tid >> 6;
    int r = blockIdx.x;
    f32x4 v = ((const f32x4*)(x + (long)r * 1024))[tid];
    ln_body(v, g, b, red, tid, lane, wid, out + (long)r * 1024);
}

// combine split-K partials + residual + bias, update x, then LN -> bf16
__global__ __launch_bounds__(256) void k_comb_ln(float* __restrict__ x,
                                                 const float* __restrict__ p01,
                                                 const float* __restrict__ bias,
                                                 const float* __restrict__ g,
                                                 const float* __restrict__ b,
                                                 u16* __restrict__ out) {
    __shared__ float red[8];
    int tid = threadIdx.x, lane = tid & 63, wid = tid >> 6;
    int r = blockIdx.x;
    f32x4 v = ((const f32x4*)(x + (long)r * 1024))[tid];
    f32x4 p0 = ((const f32x4*)(p01 + (long)r * 1024))[tid];
    f32x4 p1 = ((const f32x4*)(p01 + 2048L * 1024 + (long)r * 1024))[tid];
    f32x4 bv = ((const f32x4*)bias)[tid];
    v.x += p0.x + p1.x + bv.x; v.y += p0.y + p1.y + bv.y;
    v.z += p0.z + p1.z + bv.z; v.w += p0.w + p1.w + bv.w;
    ((f32x4*)(x + (long)r * 1024))[tid] = v;
    ln_body(v, g, b, red, tid, lane, wid, out + (long)r * 1024);
}

// ---------------------------------------------------------------- transpose + cvt f32[K][N] -> bf16[N][K]
DEVI void tr_tile(const float* __restrict__ in, u16* __restrict__ out,
                  int K, int N, int k0, int n0, int tid, float (*tile)[65]) {
    int trow = tid >> 4;
    int tcol = (tid & 15) * 4;
#pragma unroll
    for (int p = 0; p < 4; ++p) {
        int k = k0 + trow + p * 16;
        const float* src = in + (long)k * N + n0 + tcol;
#pragma unroll
        for (int j = 0; j < 4; ++j) {
            int n = n0 + tcol + j;
            tile[trow + p * 16][tcol + j] = (n < N) ? src[j] : 0.0f;
        }
    }
    __syncthreads();
#pragma unroll
    for (int p = 0; p < 4; ++p) {
        int n = n0 + trow + p * 16;
        if (n < N) {
            us4 o4;
#pragma unroll
            for (int j = 0; j < 4; ++j) o4[j] = f2bf(tile[tcol + j][trow + p * 16]);
            *(us4*)(out + (long)n * K + k0 + tcol) = o4;
        }
    }
}

__global__ __launch_bounds__(256) void k_tr_one(const float* __restrict__ in,
                                                u16* __restrict__ out, int K, int N) {
    __shared__ float tile[64][65];
    tr_tile(in, out, K, N, blockIdx.y * 64, blockIdx.x * 64, threadIdx.x, tile);
}

__global__ __launch_bounds__(256) void k_tr_layer(
    const float* __restrict__ wq, const float* __restrict__ wk,
    const float* __restrict__ wv, const float* __restrict__ wp,
    const float* __restrict__ f1, const float* __restrict__ f2,
    u16* __restrict__ oqkv, u16* __restrict__ oproj,
    u16* __restrict__ of1, u16* __restrict__ of2) {
    __shared__ float tile[64][65];
    int id = blockIdx.x;
    const float* in; u16* out; int K, N, txx, tyy;
    if (id < 1024) {
        int t = id >> 8, s2 = id & 255;
        txx = s2 & 15; tyy = s2 >> 4; K = 1024; N = 1024;
        in = (t == 0) ? wq : (t == 1) ? wk : (t == 2) ? wv : wp;
        out = (t == 3) ? oproj : oqkv + (long)t * 1024 * 1024;
    } else if (id < 2048) {
        int s2 = id - 1024;
        txx = s2 & 63; tyy = s2 >> 6; K = 1024; N = 4096; in = f1; out = of1;
    } else {
        int s2 = id - 2048;
        txx = s2 & 15; tyy = s2 >> 4; K = 4096; N = 1024; in = f2; out = of2;
    }
    tr_tile(in, out, K, N, tyy * 64, txx * 64, threadIdx.x, tile);
}

// ---------------------------------------------------------------- staging (XOR-swizzled, global_load_lds 16B)
// 64-col tiles, 256 threads (8 chunks/row, slot ^= row&7) — measured 0-conflict frag pattern
template <int ROWS>
DEVI void stage_tile(const u16* __restrict__ g, long row0, long rowmax, int ld,
                     int col0, char* lds, int tid) {
    constexpr int NCH = ROWS * 8;
#pragma unroll
    for (int p = 0; p < NCH / 256; ++p) {
        int c = tid + p * 256;
        int row = c >> 3;
        int gslot = c & 7;
        int gdata = gslot ^ (row & 7);
        long gr = row0 + row;
        if (gr > rowmax) gr = rowmax;
        const u16* src = g + gr * (long)ld + col0 + gdata * 8;
        char* dst = lds + ((long)((tid & 192) + p * 256)) * 16;
        __builtin_amdgcn_global_load_lds(
            (const __attribute__((address_space(1))) void*)src,
            (__attribute__((address_space(3))) void*)dst, 16, 0, 0);
    }
}

// 32-col tiles, 512 threads (4 chunks/row); slot s=(d+(row>>1))&3 — conflict-free (r13/r14)
template <int ROWS>
DEVI void stage32b512(const u16* __restrict__ g, long row0, long rowmax, int ld,
                      int col0, char* lds, int tid) {
    constexpr int NP = ROWS * 4 / 512;
#pragma unroll
    for (int p = 0; p < NP; ++p) {
        int c = tid + p * 512;
        int row = c >> 2;
        int gslot = c & 3;
        int gdata = (gslot - (row >> 1)) & 3;
        long gr = row0 + row;
        if (gr > rowmax) gr = rowmax;
        const u16* src = g + gr * (long)ld + col0 + gdata * 8;
        char* dst = lds + ((long)((tid & 448) + p * 512)) * 16;
        __builtin_amdgcn_global_load_lds(
            (const __attribute__((address_space(1))) void*)src,
            (__attribute__((address_space(3))) void*)dst, 16, 0, 0);
    }
}

// ---------------------------------------------------------------- per-layer GEMM (128 x BN, m97 structure)
template <int BN, int OCC, bool OUT_BF16, bool RELU, bool HAS_BIAS, bool HAS_RES, bool SPLITK>
__global__ __launch_bounds__(256, OCC) void k_gemm(
    const u16* __restrict__ A, const u16* __restrict__ Bt,
    const float* __restrict__ bias, const float* __restrict__ res,
    float* __restrict__ Cf, u16* __restrict__ Cb,
    int M, int N, int K, int ldk, int ldc) {
    constexpr int NR = BN / 32;
    constexpr int ASZ = 128 * 64 * 2;
    constexpr int BSZ = BN * 64 * 2;
    __shared__ __align__(16) char lds[2 * (ASZ + BSZ)];
    int tid = threadIdx.x, lane = tid & 63, wid = tid >> 6;
    int l15 = lane & 15, l4 = lane >> 4;
    int wr = wid >> 1, wc = wid & 1;
    if constexpr (SPLITK) {
        int h = blockIdx.z;
        A += (long)h * K;
        Bt += (long)h * K;
        Cf += (long)h * M * (long)ldc;
    }
    long m0 = (long)blockIdx.y * 128;
    long n0 = (long)blockIdx.x * BN;
    f32x4 acc[4][NR] = {};
    const int nk = K >> 6;

    stage_tile<128>(A, m0, (long)M - 1, ldk, 0, lds, tid);
    stage_tile<BN>(Bt, n0, (long)N - 1, ldk, 0, lds + ASZ, tid);
    int cur = 0;
    for (int kt = 0; kt < nk; ++kt) {
        __syncthreads();
        if (kt + 1 < nk) {
            char* nb = lds + (cur ^ 1) * (ASZ + BSZ);
            stage_tile<128>(A, m0, (long)M - 1, ldk, (kt + 1) << 6, nb, tid);
            stage_tile<BN>(Bt, n0, (long)N - 1, ldk, (kt + 1) << 6, nb + ASZ, tid);
        }
        const char* ab = lds + cur * (ASZ + BSZ);
        const char* bb = ab + ASZ;
#pragma unroll
        for (int kh = 0; kh < 2; ++kh) {
            bf16x8 af[4], bfv[NR];
#pragma unroll
            for (int mi = 0; mi < 4; ++mi) {
                int row = wr * 64 + mi * 16 + l15;
                int slot = (kh * 4 + l4) ^ (row & 7);
                af[mi] = *(const bf16x8*)(ab + (row * 8 + slot) * 16);
            }
#pragma unroll
            for (int ni = 0; ni < NR; ++ni) {
                int row = wc * (BN / 2) + ni * 16 + l15;
                int slot = (kh * 4 + l4) ^ (row & 7);
                bfv[ni] = *(const bf16x8*)(bb + (row * 8 + slot) * 16);
            }
#pragma unroll
            for (int mi = 0; mi < 4; ++mi)
#pragma unroll
                for (int ni = 0; ni < NR; ++ni)
                    acc[mi][ni] = __builtin_amdgcn_mfma_f32_16x16x32_bf16(
                        af[mi], bfv[ni], acc[mi][ni], 0, 0, 0);
        }
        cur ^= 1;
    }
#pragma unroll
    for (int ni = 0; ni < NR; ++ni) {
        long n = n0 + wc * (BN / 2) + ni * 16 + l15;
        if (n < N) {
            float bv = HAS_BIAS ? bias[n] : 0.0f;
#pragma unroll
            for (int mi = 0; mi < 4; ++mi) {
#pragma unroll
                for (int j = 0; j < 4; ++j) {
                    long m = m0 + wr * 64 + mi * 16 + l4 * 4 + j;
                    float v = acc[mi][ni][j] + bv;
                    if (HAS_RES) v += res[m * (long)ldc + n];
                    if (RELU) v = fmaxf(v, 0.0f);
                    if (OUT_BF16) Cb[m * (long)ldc + n] = f2bf(v);
                    else Cf[m * (long)ldc + n] = v;
                }
            }
        }
    }
}

// ---------------------------------------------------------------- head GEMM (r14 best: 256x128, BK=32, 512 thr,
// 66 KB -> 2 blocks/CU, conflict-free swizzle, spread grid, two-pass bounce epilogue + NT stores + LSE)
__global__ __launch_bounds__(512, 2) void k_head(
    const u16* __restrict__ A, const u16* __restrict__ Bt,
    const float* __restrict__ bias, float* __restrict__ Cf,
    float2* __restrict__ part, int M, int N, int K, int ldc) {
    constexpr int ASZ = 256 * 32 * 2;      // 16 KB
    constexpr int BSZ = 128 * 32 * 2;      // 8 KB
    constexpr int TSZ = ASZ + BSZ;         // 24 KB
    __shared__ __align__(16) char lds[128 * 129 * 4];
    int tid = threadIdx.x, lane = tid & 63, wid = tid >> 6;
    int l15 = lane & 15, l4 = lane >> 4;
    int wr = wid >> 1, wc = wid & 1;       // 4 x 2 waves; wave owns 64 x 64
    int bn = blockIdx.x, bm = blockIdx.y;
    long m0 = (long)bm * 256, n0 = (long)bn * 128;
    f32x4 acc[4][4] = {};
    const int nk = K >> 5;                 // 32

    stage32b512<256>(A, m0, (long)M - 1, K, 0, lds, tid);
    stage32b512<128>(Bt, n0, (long)N - 1, K, 0, lds + ASZ, tid);
    int cur = 0;
    for (int kt = 0; kt < nk; ++kt) {
        __syncthreads();
        if (kt + 1 < nk) {
            char* nb = lds + (cur ^ 1) * TSZ;
            stage32b512<256>(A, m0, (long)M - 1, K, (kt + 1) << 5, nb, tid);
            stage32b512<128>(Bt, n0, (long)N - 1, K, (kt + 1) << 5, nb + ASZ, tid);
        }
        const char* ab = lds + cur * TSZ;
        const char* bb = ab + ASZ;
        bf16x8 af[4], bfv[4];
#pragma unroll
        for (int mi = 0; mi < 4; ++mi) {
            int row = wr * 64 + mi * 16 + l15;
            int slot = (l4 + (row >> 1)) & 3;
            af[mi] = *(const bf16x8*)(ab + (row * 4 + slot) * 16);
        }
#pragma unroll
        for (int ni = 0; ni < 4; ++ni) {
            int row = wc * 64 + ni * 16 + l15;
            int slot = (l4 + (row >> 1)) & 3;
            bfv[ni] = *(const bf16x8*)(bb + (row * 4 + slot) * 16);
        }
#pragma unroll
        for (int mi = 0; mi < 4; ++mi)
#pragma unroll
            for (int ni = 0; ni < 4; ++ni)
                acc[mi][ni] = __builtin_amdgcn_mfma_f32_16x16x32_bf16(
                    af[mi], bfv[ni], acc[mi][ni], 0, 0, 0);
        cur ^= 1;
    }
    const float BIG_NEG = -1e30f;
    float bvv[4];
#pragma unroll
    for (int ni = 0; ni < 4; ++ni) {
        long n = n0 + wc * 64 + ni * 16 + l15;
        bvv[ni] = (n < N) ? bias[n] : 0.0f;
    }
    float* ldsF = (float*)lds;             // [128][129]
#pragma unroll
    for (int pass = 0; pass < 2; ++pass) {
        int rbase = pass * 128;
        __syncthreads();
        if ((wr >> 1) == pass) {
#pragma unroll
            for (int mi = 0; mi < 4; ++mi)
#pragma unroll
                for (int ni = 0; ni < 4; ++ni)
#pragma unroll
                    for (int j = 0; j < 4; ++j) {
                        int row = wr * 64 + mi * 16 + l4 * 4 + j - rbase;
                        int col = wc * 64 + ni * 16 + l15;
                        long n = n0 + col;
                        float v = acc[mi][ni][j] + bvv[ni];
                        if (n >= N) v = BIG_NEG;
                        ldsF[row * 129 + col] = v;
                    }
        }
        __syncthreads();
#pragma unroll 4
        for (int i = 0; i < 32; ++i) {
            int flat = tid + (i << 9);
            int row = flat >> 7, col = flat & 127;
            long n = n0 + col;
            if (n < N)
                __builtin_nontemporal_store(ldsF[row * 129 + col],
                                            &Cf[(m0 + rbase + row) * (long)ldc + n]);
        }
        if (tid < 256) {
            int r = tid >> 1, half = tid & 1;
            const float* rp = ldsF + r * 129 + half * 64;
            float mx = BIG_NEG;
#pragma unroll 8
            for (int c = 0; c < 64; ++c) mx = fmaxf(mx, rp[c]);
            float sm = 0.f;
#pragma unroll 8
            for (int c = 0; c < 64; ++c) sm += __expf(rp[c] - mx);
            float mo = __shfl_xor(mx, 1), so = __shfl_xor(sm, 1);
            float nm = fmaxf(mx, mo);
            float S = sm * __expf(mx - nm) + so * __expf(mo - nm);
            if (half == 0)
                part[(long)bn * M + m0 + rbase + r] = make_float2(nm, S);
        }
    }
}

// ---------------------------------------------------------------- MFMA attention, q-split:
// grid (256 bh, 2 q-halves); each block: 4 waves x 16 q-rows = 64 rows. K/V staged in full.
// LDS 48 KB -> 2 blocks/CU (vs 1 before) to cover latency.
__global__ __launch_bounds__(256) void k_attn_mfma(const u16* __restrict__ qkv,
                                                   u16* __restrict__ o) {
    __shared__ __align__(16) u16 Ks[128 * 64];
    __shared__ __align__(16) u16 Vt[64 * 128];
    __shared__ __align__(16) u16 Ps[4][16 * 128];
    int tid = threadIdx.x, lane = tid & 63, w = tid >> 6;
    int l15 = lane & 15, l4 = lane >> 4;
    int b = blockIdx.x >> 4, h = blockIdx.x & 15;
    int q0 = blockIdx.y * 64;
    const u16* base = qkv + (long)b * 128 * 3072 + h * 64;

    stage_tile<128>(base + 1024, 0, 127, 3072, 0, (char*)Ks, tid);
    {
        const u16* vg = base + 2048;
#pragma unroll
        for (int p = 0; p < 4; ++p) {
            int s0 = (w * 4 + p) * 8;
            u16 tmp[8];
#pragma unroll
            for (int j = 0; j < 8; ++j) tmp[j] = vg[(long)(s0 + j) * 3072 + lane];
            int slot = (s0 >> 3) ^ (lane & 7);
            *(bf16x8*)((char*)Vt + lane * 256 + slot * 16) = *(bf16x8*)tmp;
        }
    }
    // Q fragments: wave w owns rows q0 + w*16 .. +15
    bf16x8 aq[2];
#pragma unroll
    for (int kk = 0; kk < 2; ++kk)
        aq[kk] = *(const bf16x8*)(base + (long)(q0 + w * 16 + l15) * 3072 + kk * 32 + l4 * 8);
    __syncthreads();

    // S = Q K^T  (16 x 128 per wave)
    f32x4 sacc[8] = {};
#pragma unroll
    for (int sj = 0; sj < 8; ++sj) {
        bf16x8 bk[2];
#pragma unroll
        for (int kk = 0; kk < 2; ++kk) {
            int row = sj * 16 + l15;
            int slot = (kk * 4 + l4) ^ (row & 7);
            bk[kk] = *(const bf16x8*)((char*)Ks + (row * 8 + slot) * 16);
        }
        sacc[sj] = __builtin_amdgcn_mfma_f32_16x16x32_bf16(aq[0], bk[0], sacc[sj], 0, 0, 0);
        sacc[sj] = __builtin_amdgcn_mfma_f32_16x16x32_bf16(aq[1], bk[1], sacc[sj], 0, 0, 0);
    }
    const float scale = 0.03125f;
#pragma unroll
    for (int j = 0; j < 4; ++j) {
        int tq = q0 + w * 16 + l4 * 4 + j;
        float mx = -INFINITY;
#pragma unroll
        for (int sj = 0; sj < 8; ++sj) {
            int s = sj * 16 + l15;
            float v = (s <= tq) ? sacc[sj][j] * scale : -INFINITY;
            sacc[sj][j] = v;
            mx = fmaxf(mx, v);
        }
#pragma unroll
        for (int ofs = 1; ofs < 16; ofs <<= 1) mx = fmaxf(mx, __shfl_xor(mx, ofs));
        float sm = 0.f;
#pragma unroll
        for (int sj = 0; sj < 8; ++sj) {
            float e = __expf(sacc[sj][j] - mx);
            sacc[sj][j] = e;
            sm += e;
        }
#pragma unroll
        for (int ofs = 1; ofs < 16; ofs <<= 1) sm += __shfl_xor(sm, ofs);
        float inv = 1.0f / sm;
        int m2 = l4 * 4 + j;               // P row within wave: 0..15
        u16* prow = Ps[w] + m2 * 128;
#pragma unroll
        for (int sj = 0; sj < 8; ++sj) {
            int s = sj * 16 + l15;
            int slot = (s >> 3) ^ (m2 & 7);
            prow[slot * 8 + (s & 7)] = f2bf(sacc[sj][j] * inv);
        }
    }
    // O = P V  (16 x 64 per wave); P reads are wave-private
    f32x4 oacc[4] = {};
#pragma unroll
    for (int kk = 0; kk < 4; ++kk) {
        bf16x8 pa, bv[4];
        {
            int m2 = l15;                  // 0..15
            int slot = (kk * 4 + l4) ^ (m2 & 7);
            pa = *(const bf16x8*)((char*)(Ps[w]) + m2 * 256 + slot * 16);
        }
#pragma unroll
        for (int nb = 0; nb < 4; ++nb) {
            int d = nb * 16 + l15;
            int slot = (kk * 4 + l4) ^ (d & 7);
            bv[nb] = *(const bf16x8*)((char*)Vt + d * 256 + slot * 16);
        }
#pragma unroll
        for (int nb = 0; nb < 4; ++nb)
            oacc[nb] = __builtin_amdgcn_mfma_f32_16x16x32_bf16(pa, bv[nb], oacc[nb], 0, 0, 0);
    }
#pragma unroll
    for (int nb = 0; nb < 4; ++nb) {
        int d = nb * 16 + l15;
#pragma unroll
        for (int j = 0; j < 4; ++j) {
            int tq = q0 + w * 16 + l4 * 4 + j;
            o[((long)b * 128 + tq) * 1024 + h * 64 + d] = f2bf(oacc[nb][j]);
        }
    }
}

// ---------------------------------------------------------------- loss from partials (part layout: [bn][2048])
__global__ __launch_bounds__(64) void k_loss_rows2(const float2* __restrict__ part,
                                                   const float* __restrict__ logits,
                                                   const int* __restrict__ tgt,
                                                   float* __restrict__ rowloss, int ncb) {
    int r = blockIdx.x, lane = threadIdx.x;
    float M = -1e30f, S = 0.f;
    for (int cb = lane; cb < ncb; cb += 64) {
        float2 p = part[(long)cb * 2048 + r];
        float nm = fmaxf(M, p.x);
        S = S * __expf(M - nm) + p.y * __expf(p.x - nm);
        M = nm;
    }
#pragma unroll
    for (int ofs = 32; ofs; ofs >>= 1) {
        float M2 = __shfl_xor(M, ofs), S2 = __shfl_xor(S, ofs);
        float nm = fmaxf(M, M2);
        S = S * __expf(M - nm) + S2 * __expf(M2 - nm);
        M = nm;
    }
    if (lane == 0)
        rowloss[r] = (M + logf(S)) - logits[(long)r * 50257 + tgt[r]];
}

__global__ __launch_bounds__(256) void k_loss_reduce(const float* __restrict__ rowloss,
                                                     float* __restrict__ out) {
    __shared__ float red[4];
    int tid = threadIdx.x, lane = tid & 63, wid = tid >> 6;
    float s = 0.f;
    for (int i = tid; i < 2048; i += 256) s += rowloss[i];
#pragma unroll
    for (int ofs = 32; ofs; ofs >>= 1) s += __shfl_xor(s, ofs);
    if (lane == 0) red[wid] = s;
    __syncthreads();
    if (tid == 0) out[0] = (red[0] + red[1] + red[2] + red[3]) * (1.0f / 2048.0f);
}

// ---------------------------------------------------------------- host
extern "C" void kernel_launch(void* const* d_in, const int* in_sizes, int n_in,
                              void* d_out, int out_size, void* d_ws, size_t ws_size,
                              hipStream_t stream) {
    (void)in_sizes; (void)n_in; (void)out_size; (void)ws_size;
    const int*   idx     = (const int*)d_in[0];
    const int*   targets = (const int*)d_in[1];
    const float* tok_emb = (const float*)d_in[2];
    const float* pos_emb = (const float*)d_in[3];
    const float* wq      = (const float*)d_in[4];
    const float* wk      = (const float*)d_in[5];
    const float* wv      = (const float*)d_in[6];
    const float* w_proj  = (const float*)d_in[7];
    const float* b_proj  = (const float*)d_in[8];
    const float* ln1_g   = (const float*)d_in[9];
    const float* ln1_b   = (const float*)d_in[10];
    const float* ln2_g   = (const float*)d_in[11];
    const float* ln2_b   = (const float*)d_in[12];
    const float* w_fc1   = (const float*)d_in[13];
    const float* b_fc1   = (const float*)d_in[14];
    const float* w_fc2   = (const float*)d_in[15];
    const float* b_fc2   = (const float*)d_in[16];
    const float* lnf_g   = (const float*)d_in[17];
    const float* lnf_b   = (const float*)d_in[18];
    const float* w_head  = (const float*)d_in[19];
    const float* b_head  = (const float*)d_in[20];
    float* out = (float*)d_out;

    char* w = (char*)d_ws;
    auto alloc = [&](size_t bytes) {
        char* p = w;
        w += (bytes + 255) & ~(size_t)255;
        return p;
    };
    u16*    wT_qkv  = (u16*)alloc(3072L * 1024 * 2);
    u16*    wT_proj = (u16*)alloc(1024L * 1024 * 2);
    u16*    wT_f1   = (u16*)alloc(4096L * 1024 * 2);
    u16*    wT_f2   = (u16*)alloc(1024L * 4096 * 2);
    u16*    wT_head = (u16*)alloc(50257L * 1024 * 2);
    float*  x       = (float*)alloc(2048L * 1024 * 4);
    u16*    h_bf    = (u16*)alloc(2048L * 1024 * 2);
    u16*    qkvb    = (u16*)alloc(2048L * 3072 * 2);
    u16*    o_bf    = (u16*)alloc(2048L * 1024 * 2);
    u16*    ff_bf   = (u16*)alloc(2048L * 4096 * 2);
    float*  p01     = (float*)alloc(2L * 2048 * 1024 * 4);   // split-K partials
    float2* part    = (float2*)alloc(393L * 2048 * 8);
    float*  rowloss = (float*)alloc(2048L * 4);

    k_embed<<<2048, 256, 0, stream>>>(idx, tok_emb, pos_emb, x);
    k_tr_one<<<dim3(786, 16), 256, 0, stream>>>(w_head, wT_head, 1024, 50257);

    for (int l = 0; l < 12; ++l) {
        k_tr_layer<<<3072, 256, 0, stream>>>(
            wq + (long)l * 1048576, wk + (long)l * 1048576,
            wv + (long)l * 1048576, w_proj + (long)l * 1048576,
            w_fc1 + (long)l * 4194304, w_fc2 + (long)l * 4194304,
            wT_qkv, wT_proj, wT_f1, wT_f2);
        if (l == 0)
            k_ln<<<2048, 256, 0, stream>>>(x, ln1_g, ln1_b, h_bf);
        else
            k_comb_ln<<<2048, 256, 0, stream>>>(x, p01, b_fc2 + (l - 1) * 1024,
                                                ln1_g + l * 1024, ln1_b + l * 1024, h_bf);
        k_gemm<128, 2, true, false, false, false, false><<<dim3(24, 16), 256, 0, stream>>>(
            h_bf, wT_qkv, nullptr, nullptr, nullptr, qkvb, 2048, 3072, 1024, 1024, 3072);
        k_attn_mfma<<<dim3(256, 2), 256, 0, stream>>>(qkvb, o_bf);
        // proj split-K x2 at 3 blocks/CU; combine + b_proj fused into ln2 comb
        k_gemm<64, 3, false, false, false, false, true><<<dim3(16, 16, 2), 256, 0, stream>>>(
            o_bf, wT_proj, nullptr, nullptr, p01, nullptr, 2048, 1024, 512, 1024, 1024);
        k_comb_ln<<<2048, 256, 0, stream>>>(x, p01, b_proj + l * 1024,
                                            ln2_g + l * 1024, ln2_b + l * 1024, h_bf);
        k_gemm<128, 2, true, true, true, false, false><<<dim3(32, 16), 256, 0, stream>>>(
            h_bf, wT_f1, b_fc1 + l * 4096, nullptr, nullptr, ff_bf, 2048, 4096, 1024, 1024, 4096);
        // fc2 split-K x2 at 3 blocks/CU; combine fused into next layer's ln1 comb (or final lnf)
        k_gemm<64, 3, false, false, false, false, true><<<dim3(16, 16, 2), 256, 0, stream>>>(
            ff_bf, wT_f2, nullptr, nullptr, p01, nullptr, 2048, 1024, 2048, 4096, 1024);
    }
    k_comb_ln<<<2048, 256, 0, stream>>>(x, p01, b_fc2 + 11 * 1024, lnf_g, lnf_b, h_bf);
    k_head<<<dim3(393, 8), 512, 0, stream>>>(h_bf, wT_head, b_head, out, part,
                                             2048, 50257, 1024, 50257);
    k_loss_rows2<<<2048, 64, 0, stream>>>(part, out, targets, rowloss, 393);
    k_loss_reduce<<<1, 256, 0, stream>>>(rowloss, out + 102926336L);
}